// Round 3
// baseline (341.164 us; speedup 1.0000x reference)
//
#include <hip/hip_runtime.h>

// out[b,i,n] = sum_j w[i,j] * x[b,j,n]
// x: [B=256, 3, N=65536] fp32, w: [3,3] fp32, out: [B, 3, N] fp32.
// HBM-bound streaming map: 402.7 MB total traffic, floor ~64 us @ 6.3 TB/s.
// R3: same as R2 but with native clang vector type (ext_vector_type(4)) so
// __builtin_nontemporal_store compiles: 4 groups/thread (12 outstanding
// loads for MLP), nontemporal float4 stores (pure streaming, skip cache).

typedef float f32x4 __attribute__((ext_vector_type(4)));

#define B_DIM 256
#define N_DIM 65536
#define GPB   (N_DIM / 4)                    // float4 groups per (b,j) row = 16384
#define TOTAL_GROUPS ((long)B_DIM * GPB)     // 4,194,304
#define PER_THREAD 4

__global__ __launch_bounds__(256) void rot_kernel(
    const f32x4* __restrict__ x,
    const float* __restrict__ w,
    f32x4*       __restrict__ out)
{
    const long t      = (long)blockIdx.x * blockDim.x + threadIdx.x;
    const long stride = TOTAL_GROUPS / PER_THREAD;   // 1,048,576 (coalescing-preserving phase stride)

    // 3x3 weight: wave-uniform -> scalar loads, cached
    const float w00 = w[0], w01 = w[1], w02 = w[2];
    const float w10 = w[3], w11 = w[4], w12 = w[5];
    const float w20 = w[6], w21 = w[7], w22 = w[8];

    long  base[PER_THREAD];
    f32x4 x0[PER_THREAD], x1[PER_THREAD], x2[PER_THREAD];

    // Issue all loads first -> 12 outstanding global loads per thread
#pragma unroll
    for (int k = 0; k < PER_THREAD; ++k) {
        const long idx = t + (long)k * stride;
        const long b   = idx >> 14;            // / GPB
        const long g   = idx & (GPB - 1);      // % GPB
        base[k] = b * (3L * GPB) + g;
        x0[k] = x[base[k]];
        x1[k] = x[base[k] + GPB];
        x2[k] = x[base[k] + 2 * GPB];
    }

#pragma unroll
    for (int k = 0; k < PER_THREAD; ++k) {
        f32x4 o0, o1, o2;
        // vector FMAs: whole f32x4 at once (element-wise)
        o0 = w00 * x0[k] + w01 * x1[k] + w02 * x2[k];
        o1 = w10 * x0[k] + w11 * x1[k] + w12 * x2[k];
        o2 = w20 * x0[k] + w21 * x1[k] + w22 * x2[k];

        __builtin_nontemporal_store(o0, &out[base[k]]);
        __builtin_nontemporal_store(o1, &out[base[k] + GPB]);
        __builtin_nontemporal_store(o2, &out[base[k] + 2 * GPB]);
    }
}

extern "C" void kernel_launch(void* const* d_in, const int* in_sizes, int n_in,
                              void* d_out, int out_size, void* d_ws, size_t ws_size,
                              hipStream_t stream)
{
    const f32x4* x = (const f32x4*)d_in[0];
    const float* w = (const float*)d_in[1];
    f32x4*       o = (f32x4*)d_out;

    const long threads = TOTAL_GROUPS / PER_THREAD;   // 1,048,576
    const int  block   = 256;
    const long grid    = threads / block;             // 4096 blocks, exact

    rot_kernel<<<dim3((unsigned)grid), dim3(block), 0, stream>>>(x, w, o);
}